// Round 6
// baseline (495.800 us; speedup 1.0000x reference)
//
#include <hip/hip_runtime.h>
#include <stdint.h>

// Match numpy f32 elementwise semantics: no implicit FMA contraction.
#pragma clang fp contract(off)

#define GRIDN 256
#define NC (GRIDN * GRIDN)
#define RESN 512
#define RBLOCKS 256
#define CAP 1024      // per-cell sort capacity
#define CPB 16        // cells per cellsort block (fallback path)
#define NB 32         // tri chunks (chunk=3125 << u16 range)
#define NS 16         // cell-space slices (4096 cells = 16 grid rows = 8KB LDS)
#define SBINS 2048    // packed u32 bins per slice
#define MAXGRID 1024  // __launch_bounds__(256,4) -> 4 blocks/CU x 256 CUs

// NOTE (r1): GLOBAL per-cell RETURNING atomics: 154->2403us. Do not retry.
// NOTE (r3): row-parallel full-tbox re-stream per grid row: 158->368us. Do not retry.
// NOTE (r5): tile-fused bin (625 blocks x full tbox stream, 33KB LDS): 346us,
//   k_bin=246us @0.26% occupancy. Same redundant-streaming trap. Do not retry.
// NOTE (r6 = this round): 9-launch pipeline is launch-overhead-bound (~10us/launch
//   x 9 ~= 90us of the 155; calibrated from r5: 5 launches - work ~= 50us overhead).
//   Same r4 phase math, ONE persistent kernel + manual grid barriers (grid sized
//   from occupancy query -> co-resident; device-scope atomics; spin-capped).
//   Fallback = exact r4 multi-kernel path if the query fails.

typedef unsigned short bfraw;
typedef unsigned short u16;

__device__ __forceinline__ float bf2f(bfraw h) {
    return __uint_as_float(((uint32_t)h) << 16);   // bf16 upcast is exact
}
__device__ __forceinline__ bfraw f2bf(float f) {
    uint32_t b = __float_as_uint(f);               // RNE f32 -> bf16
    return (bfraw)((b + 0x7FFFu + ((b >> 16) & 1u)) >> 16);
}
__device__ __forceinline__ uint32_t fkey(float f) {
    uint32_t b = __float_as_uint(f);
    return (b & 0x80000000u) ? ~b : (b | 0x80000000u);
}

// ---------------- manual grid barrier (count/generation, device scope) ----------
__device__ __forceinline__ void gsync(uint32_t* cnt, uint32_t* gen, int nb) {
    __syncthreads();
    if (threadIdx.x == 0) {
        __threadfence();
        uint32_t g = atomicAdd(gen, 0u);          // device-scope load
        uint32_t a = atomicAdd(cnt, 1u);
        if (a == (uint32_t)nb - 1u) {
            atomicExch(cnt, 0u);
            __threadfence();
            atomicAdd(gen, 1u);                   // release next generation
        } else {
            long spins = 0;
            while (atomicAdd(gen, 0u) == g) {
                __builtin_amdgcn_s_sleep(2);
                if (++spins > 100000000L) break;  // no-hang safety
            }
        }
        __threadfence();
    }
    __syncthreads();
}

// ================= shared phase bodies (mega kernel AND fallback) ===============

__device__ void dev_reduce_partial(const bfraw* __restrict__ u, int nrows, int task,
                                   int t, double* ssum, float* smin, float* smax,
                                   double* __restrict__ psum,
                                   float* __restrict__ pmin,
                                   float* __restrict__ pmax) {
    double s0 = 0.0, s1 = 0.0, s2 = 0.0;
    float mn0 = INFINITY, mn1 = INFINITY, mn2 = INFINITY;
    float mx0 = -INFINITY, mx1 = -INFINITY, mx2 = -INFINITY;
    for (int r = task * 256 + t; r < nrows; r += 256 * RBLOCKS) {
        float a = bf2f(u[3 * r + 0]);
        float b = bf2f(u[3 * r + 1]);
        float c = bf2f(u[3 * r + 2]);
        s0 += (double)a; s1 += (double)b; s2 += (double)c;
        mn0 = fminf(mn0, a); mx0 = fmaxf(mx0, a);
        mn1 = fminf(mn1, b); mx1 = fmaxf(mx1, b);
        mn2 = fminf(mn2, c); mx2 = fmaxf(mx2, c);
    }
    ssum[t * 3 + 0] = s0; ssum[t * 3 + 1] = s1; ssum[t * 3 + 2] = s2;
    smin[t * 3 + 0] = mn0; smin[t * 3 + 1] = mn1; smin[t * 3 + 2] = mn2;
    smax[t * 3 + 0] = mx0; smax[t * 3 + 1] = mx1; smax[t * 3 + 2] = mx2;
    __syncthreads();
    for (int st = 128; st > 0; st >>= 1) {
        if (t < st) {
            for (int c = 0; c < 3; c++) {
                ssum[t * 3 + c] += ssum[(t + st) * 3 + c];
                smin[t * 3 + c] = fminf(smin[t * 3 + c], smin[(t + st) * 3 + c]);
                smax[t * 3 + c] = fmaxf(smax[t * 3 + c], smax[(t + st) * 3 + c]);
            }
        }
        __syncthreads();
    }
    if (t == 0) {
        for (int c = 0; c < 3; c++) {
            psum[task * 3 + c] = ssum[c];
            pmin[task * 3 + c] = smin[c];
            pmax[task * 3 + c] = smax[c];
        }
    }
    __syncthreads();
}

__device__ void dev_reduce_final(const double* __restrict__ psum,
                                 const float* __restrict__ pmin,
                                 const float* __restrict__ pmax,
                                 int nrows, int t,
                                 double* ssum, float* smin, float* smax,
                                 float* __restrict__ cst) {
    for (int c = 0; c < 3; c++) {
        ssum[t * 3 + c] = psum[t * 3 + c];
        smin[t * 3 + c] = pmin[t * 3 + c];
        smax[t * 3 + c] = pmax[t * 3 + c];
    }
    __syncthreads();
    for (int st = 128; st > 0; st >>= 1) {
        if (t < st) {
            for (int c = 0; c < 3; c++) {
                ssum[t * 3 + c] += ssum[(t + st) * 3 + c];
                smin[t * 3 + c] = fminf(smin[t * 3 + c], smin[(t + st) * 3 + c]);
                smax[t * 3 + c] = fmaxf(smax[t * 3 + c], smax[(t + st) * 3 + c]);
            }
        }
        __syncthreads();
    }
    if (t == 0) {
        float fn = (float)nrows;
        float m0 = (float)ssum[0] / fn;
        float m1 = (float)ssum[1] / fn;
        float m2 = (float)ssum[2] / fn;
        // fp32 rounding is monotone: max_r(u - mean) == colmax - mean exactly.
        float vmax = fmaxf(fmaxf(smax[0] - m0, smax[1] - m1), smax[2] - m2);
        float vmin = fminf(fminf(smin[0] - m0, smin[1] - m1), smin[2] - m2);
        float span = fmaxf(vmax - vmin, 1e-06f);
        float s = 0.5f / span;   // SCALE / span
        cst[0] = m0; cst[1] = m1; cst[2] = m2; cst[3] = s;
    }
    __syncthreads();
}

// tcs layout per tri (8 floats): cpx0,cpy0,cpx1,cpy1,cpx2,cpy2,shade,0
// tbox: lox | loy<<8 | hx<<16 | hy<<24  with hx=min(hix,lox+3), hy=min(hiy,loy+3)
__device__ void dev_setup_one(const bfraw* __restrict__ u,
                              const int* __restrict__ faces,
                              const bfraw* __restrict__ mvp,
                              const bfraw* __restrict__ light,
                              const float* __restrict__ cst, int f,
                              float* __restrict__ tcs,
                              uint32_t* __restrict__ tz,
                              uint32_t* __restrict__ tbox) {
    float m0 = cst[0], m1 = cst[1], m2 = cst[2], s = cst[3];
    float M[12];
    for (int i = 0; i < 12; i++) M[i] = bf2f(mvp[i]);

    float vx[3], vy[3], vz[3], cpx[3], cpy[3], zc[3];
    for (int j = 0; j < 3; j++) {
        int idx = faces[3 * f + j];
        float a = bf2f(u[3 * idx + 0]);
        float b = bf2f(u[3 * idx + 1]);
        float c = bf2f(u[3 * idx + 2]);
        float x = (a - m0) * s;
        float y = (b - m1) * s;
        float z = (c - m2) * s;
        vx[j] = x; vy[j] = y; vz[j] = z;
        // BLAS-style ascending-k fma chain; w=1 -> plain add of M[row][3]
        float cx = fmaf(x, M[0], 0.0f);
        cx = fmaf(y, M[1], cx); cx = fmaf(z, M[2], cx); cx = cx + M[3];
        float cy = fmaf(x, M[4], 0.0f);
        cy = fmaf(y, M[5], cy); cy = fmaf(z, M[6], cy); cy = cy + M[7];
        float cz = fmaf(x, M[8], 0.0f);
        cz = fmaf(y, M[9], cz); cz = fmaf(z, M[10], cz); cz = cz + M[11];
        cpx[j] = (cx + 1.0f) * 0.5f;
        cpy[j] = (cy + 1.0f) * 0.5f;
        zc[j] = cz;
    }
    float zmean = ((zc[0] + zc[1]) + zc[2]) / 3.0f;

    float e1x = vx[0] - vx[1], e1y = vy[0] - vy[1], e1z = vz[0] - vz[1];
    float e2x = vx[2] - vx[1], e2y = vy[2] - vy[1], e2z = vz[2] - vz[1];
    float nx = e1y * e2z - e1z * e2y;
    float ny = e1z * e2x - e1x * e2z;
    float nz = e1x * e2y - e1y * e2x;
    float nn = nx * nx;
    nn = nn + ny * ny;
    nn = nn + nz * nz;
    float d = sqrtf(nn) + 1e-10f;
    float inx = nx / d, iny = ny / d, inz = nz / d;

    float l0 = bf2f(light[0]), l1 = bf2f(light[1]), l2 = bf2f(light[2]);
    float p0 = (-l0) * inx;
    float p1 = (-l1) * iny;
    float p2 = (-l2) * inz;
    float shading = fmaxf((p0 + p1) + p2, 0.0f);

    tcs[f * 8 + 0] = cpx[0]; tcs[f * 8 + 1] = cpy[0];
    tcs[f * 8 + 2] = cpx[1]; tcs[f * 8 + 3] = cpy[1];
    tcs[f * 8 + 4] = cpx[2]; tcs[f * 8 + 5] = cpy[2];
    tcs[f * 8 + 6] = shading;
    tcs[f * 8 + 7] = 0.0f;

    tz[f] = fkey(zmean);

    float mnx = fminf(fminf(cpx[0], cpx[1]), cpx[2]);
    float mny = fminf(fminf(cpy[0], cpy[1]), cpy[2]);
    float mxx = fmaxf(fmaxf(cpx[0], cpx[1]), cpx[2]);
    float mxy = fmaxf(fmaxf(cpy[0], cpy[1]), cpy[2]);
    int lox = (int)floorf(mnx * 256.0f); lox = lox < 0 ? 0 : (lox > 255 ? 255 : lox);
    int loy = (int)floorf(mny * 256.0f); loy = loy < 0 ? 0 : (loy > 255 ? 255 : loy);
    int hix = (int)floorf(mxx * 256.0f); hix = hix < 0 ? 0 : (hix > 255 ? 255 : hix);
    int hiy = (int)floorf(mxy * 256.0f); hiy = hiy < 0 ? 0 : (hiy > 255 ? 255 : hiy);
    int hx = hix < lox + 3 ? hix : lox + 3;   // SPAN=4 window
    int hy = hiy < loy + 3 ? hiy : loy + 3;
    tbox[f] = (uint32_t)lox | ((uint32_t)loy << 8) | ((uint32_t)hx << 16) | ((uint32_t)hy << 24);
}

// slice sl owns grid rows [16*sl,16*sl+16): y-loop clamped, no per-cell filter
__device__ void dev_count_task(const uint32_t* __restrict__ tbox, int F,
                               u16* __restrict__ blockHist, uint32_t* hist,
                               int task, int t) {
    int b = task >> 4;
    int sl = task & (NS - 1);
    int chunk = (F + NB - 1) / NB;
    int fs = b * chunk;
    int fe = fs + chunk < F ? fs + chunk : F;
    int y0 = sl * 16, y1 = y0 + 15;
    for (int i = t; i < SBINS; i += 256) hist[i] = 0u;
    __syncthreads();
    for (int f = fs + t; f < fe; f += 256) {
        uint32_t bx = tbox[f];
        int lox = bx & 255, loy = (bx >> 8) & 255;
        int hx = (bx >> 16) & 255, hy = bx >> 24;
        int ys = loy > y0 ? loy : y0;
        int ye = hy < y1 ? hy : y1;
        for (int yy = ys; yy <= ye; yy++) {
            for (int xx = lox; xx <= hx; xx++) {
                uint32_t c = (uint32_t)(yy * GRIDN + xx) & 4095u;
                atomicAdd(&hist[c >> 1], 1u << (16u * (c & 1u)));
            }
        }
    }
    __syncthreads();
    uint32_t* dst = (uint32_t*)(blockHist + (size_t)b * NC) + sl * SBINS;
    for (int i = t; i < SBINS; i += 256) dst[i] = hist[i];
    __syncthreads();
}

// scan task B: cells [B*1024, B*1024+1024), 4 cells/thread; writes block-LOCAL
// exclusive cellOff + blockSum[B]; blockHist entries become per-(chunk,cell) base
__device__ void dev_scan_task(u16* __restrict__ blockHist,
                              uint32_t* __restrict__ cellOff,
                              uint32_t* __restrict__ blockSum,
                              uint32_t* sscan, int task, int t) {
    int c0 = task * 1024 + t * 4;
    uint32_t tot[4];
    uint32_t tsum = 0;
    for (int k = 0; k < 4; k++) {
        uint32_t tt = 0;
        for (int b = 0; b < NB; b++) {
            size_t o = (size_t)b * NC + (c0 + k);
            uint32_t v = blockHist[o];
            blockHist[o] = (u16)tt;
            tt += v;
        }
        tot[k] = tt;
        tsum += tt;
    }
    sscan[t] = tsum;
    __syncthreads();
    for (int st = 1; st < 256; st <<= 1) {
        uint32_t a = 0;
        if (t >= st) a = sscan[t - st];
        __syncthreads();
        if (t >= st) sscan[t] += a;
        __syncthreads();
    }
    uint32_t run = sscan[t] - tsum;   // exclusive
    for (int k = 0; k < 4; k++) {
        cellOff[c0 + k] = run;
        run += tot[k];
    }
    if (t == 255) blockSum[task] = sscan[255];
    __syncthreads();
}

__device__ void dev_place_task(const uint32_t* __restrict__ tbox,
                               const u16* __restrict__ blockHist,
                               const uint32_t* __restrict__ cellOff,
                               const uint32_t* pre,
                               uint32_t* __restrict__ pairs, int F,
                               uint32_t* hist, int task, int t) {
    int b = task >> 4;
    int sl = task & (NS - 1);
    int chunk = (F + NB - 1) / NB;
    int fs = b * chunk;
    int fe = fs + chunk < F ? fs + chunk : F;
    int y0 = sl * 16, y1 = y0 + 15;
    uint32_t pcap = (uint32_t)F * 16u;
    for (int i = t; i < SBINS; i += 256) hist[i] = 0u;
    __syncthreads();
    for (int f = fs + t; f < fe; f += 256) {
        uint32_t bx = tbox[f];
        int lox = bx & 255, loy = (bx >> 8) & 255;
        int hx = (bx >> 16) & 255, hy = bx >> 24;
        int ys = loy > y0 ? loy : y0;
        int ye = hy < y1 ? hy : y1;
        for (int yy = ys; yy <= ye; yy++) {
            for (int xx = lox; xx <= hx; xx++) {
                uint32_t cell = (uint32_t)(yy * GRIDN + xx);
                uint32_t c = cell & 4095u;
                uint32_t sh = 16u * (c & 1u);
                uint32_t old = atomicAdd(&hist[c >> 1], 1u << sh);
                uint32_t r = (old >> sh) & 0xFFFFu;
                uint32_t base = cellOff[cell] + (pre ? pre[cell >> 10] : 0u);
                uint32_t pos = base + (uint32_t)blockHist[(size_t)b * NC + cell] + r;
                if (pos < pcap) pairs[pos] = (uint32_t)f;   // defensive vs poisoned replay
            }
        }
    }
    __syncthreads();
}

// top-64 selection for cells with n>64 ONLY; rank-write leaves survivors SORTED
__device__ void dev_cellsort_cell(const uint32_t* __restrict__ cellOff,
                                  const uint32_t* pre,
                                  const uint32_t* __restrict__ tz,
                                  uint32_t* __restrict__ pairs, int F,
                                  uint64_t* lkeys, int cell, int t) {
    uint32_t pcap = (uint32_t)F * 16u;
    uint32_t off = cellOff[cell] + (pre ? pre[cell >> 10] : 0u);
    uint32_t end = cellOff[cell + 1] + (pre ? pre[(cell + 1) >> 10] : 0u);
    if (off > pcap || end > pcap || end < off) return;   // defensive (uniform)
    uint32_t n = end - off;
    if (n <= 64u) return;             // no truncation -> no sort needed
    uint32_t m = n > CAP ? CAP : n;
    for (uint32_t i = t; i < m; i += 256) {
        uint32_t id = pairs[off + i];
        if (id >= (uint32_t)F) id = 0;   // defensive
        lkeys[i] = ((uint64_t)tz[id] << 32) | id;
    }
    __syncthreads();
    uint64_t k0 = ~0ull, k1 = ~0ull, k2 = ~0ull, k3 = ~0ull;
    uint32_t i0 = t, i1 = t + 256, i2 = t + 512, i3 = t + 768;
    if (i0 < m) k0 = lkeys[i0];
    if (i1 < m) k1 = lkeys[i1];
    if (i2 < m) k2 = lkeys[i2];
    if (i3 < m) k3 = lkeys[i3];
    uint32_t r0 = 0, r1 = 0, r2 = 0, r3 = 0;
    for (uint32_t j = 0; j < m; j++) {
        uint64_t kj = lkeys[j];   // broadcast: conflict-free
        r0 += (kj < k0) ? 1u : 0u;
        r1 += (kj < k1) ? 1u : 0u;
        r2 += (kj < k2) ? 1u : 0u;
        r3 += (kj < k3) ? 1u : 0u;
    }
    if (i0 < m && r0 < 64u) pairs[off + r0] = (uint32_t)(k0 & 0xFFFFFFFFu);
    if (i1 < m && r1 < 64u) pairs[off + r1] = (uint32_t)(k1 & 0xFFFFFFFFu);
    if (i2 < m && r2 < 64u) pairs[off + r2] = (uint32_t)(k2 & 0xFFFFFFFFu);
    if (i3 < m && r3 < 64u) pairs[off + r3] = (uint32_t)(k3 & 0xFFFFFFFFu);
    __syncthreads();   // protect lkeys before next cell's staging (uniform)
}

// raster: first-hit (sorted, n>64) / argmin (unsorted, n<=64) — r3 invariant
__device__ void dev_raster_pixel(const float* __restrict__ tcs,
                                 const uint32_t* __restrict__ tz,
                                 const uint32_t* __restrict__ cellOff,
                                 const uint32_t* pre,
                                 const uint32_t* __restrict__ pairs,
                                 const bfraw* __restrict__ basec,
                                 const bfraw* __restrict__ bg,
                                 bfraw* __restrict__ out, int F, int p) {
    int col = p & (RESN - 1);
    int row = p >> 9;
    float px = ((float)col + 0.5f) / 512.0f;
    float py = ((float)row + 0.5f) / 512.0f;
    int cell = (row >> 1) * GRIDN + (col >> 1);
    uint32_t pcap = (uint32_t)F * 16u;
    uint32_t off = cellOff[cell] + (pre ? pre[cell >> 10] : 0u);
    uint32_t end = cellOff[cell + 1] + (pre ? pre[(cell + 1) >> 10] : 0u);
    uint32_t n = 0;
    if (off <= pcap && end <= pcap && end >= off) n = end - off;
    uint32_t m = n > 64u ? 64u : n;
    bool srt = n > 64u;
    uint64_t best = ~0ull;
    uint32_t bestId = 0u;
    float bestSh = 0.0f;
    bool found = false;
    for (uint32_t k = 0; k < m; k++) {
        uint32_t id = pairs[off + k];
        if (id >= (uint32_t)F) continue;   // defensive
        const float4 A = *(const float4*)(tcs + (size_t)id * 8);
        const float4 B = *(const float4*)(tcs + (size_t)id * 8 + 4);
        float ax = A.x, ay = A.y, bx = A.z, by = A.w, cx = B.x, cy = B.y;
        float e0 = (bx - ax) * (py - ay) - (by - ay) * (px - ax);
        float e1 = (cx - bx) * (py - by) - (cy - by) * (px - bx);
        float e2 = (ax - cx) * (py - cy) - (ay - cy) * (px - cx);
        bool inside = (e0 >= 0.0f && e1 >= 0.0f && e2 >= 0.0f) ||
                      (e0 <= 0.0f && e1 <= 0.0f && e2 <= 0.0f);
        if (inside) {
            if (srt) { bestId = id; bestSh = B.z; found = true; break; }
            uint64_t key = ((uint64_t)tz[id] << 32) | id;
            if (key < best) { best = key; bestId = id; bestSh = B.z; found = true; }
        }
    }
    float r, g, b;
    if (found) {
        r = bf2f(basec[3 * bestId + 0]) * bestSh;
        g = bf2f(basec[3 * bestId + 1]) * bestSh;
        b = bf2f(basec[3 * bestId + 2]) * bestSh;
    } else {
        r = bf2f(bg[0]); g = bf2f(bg[1]); b = bf2f(bg[2]);
    }
    int o = p * 3;
    out[o + 0] = f2bf(r);
    out[o + 1] = f2bf(g);
    out[o + 2] = f2bf(b);
}

// ================= persistent mega kernel (one launch, 8 phases) ================
__global__ void __launch_bounds__(256, 4)
k_mega(const bfraw* __restrict__ u, const int* __restrict__ faces,
       const bfraw* __restrict__ mvp, const bfraw* __restrict__ light,
       const bfraw* __restrict__ bg, const bfraw* __restrict__ basec,
       int nrows, int F,
       double* __restrict__ psum, float* __restrict__ pmin, float* __restrict__ pmax,
       float* __restrict__ cst, float* __restrict__ tcs,
       uint32_t* __restrict__ tz, uint32_t* __restrict__ tbox,
       u16* __restrict__ blockHist, uint32_t* __restrict__ cellOff,
       uint32_t* __restrict__ blockSum, uint32_t* __restrict__ pairs,
       bfraw* __restrict__ out, uint32_t* bcnt, uint32_t* bgen) {
    int t = threadIdx.x;
    int nb = gridDim.x;
    __shared__ double ssum[768];
    __shared__ float smin[768];
    __shared__ float smax[768];
    __shared__ uint32_t hist[SBINS];
    __shared__ uint64_t lkeys[CAP];
    __shared__ uint32_t sscan[256];
    __shared__ uint32_t pre[65];

    // P0: partial reduce
    for (int task = blockIdx.x; task < RBLOCKS; task += nb)
        dev_reduce_partial(u, nrows, task, t, ssum, smin, smax, psum, pmin, pmax);
    gsync(bcnt, bgen, nb);
    // P1: finalize cst
    if (blockIdx.x == 0)
        dev_reduce_final(psum, pmin, pmax, nrows, t, ssum, smin, smax, cst);
    gsync(bcnt, bgen, nb);
    // P2: setup
    int FB = (F + 255) >> 8;
    for (int task = blockIdx.x; task < FB; task += nb) {
        int f = task * 256 + t;
        if (f < F) dev_setup_one(u, faces, mvp, light, cst, f, tcs, tz, tbox);
    }
    gsync(bcnt, bgen, nb);
    // P3: count
    for (int task = blockIdx.x; task < NB * NS; task += nb)
        dev_count_task(tbox, F, blockHist, hist, task, t);
    gsync(bcnt, bgen, nb);
    // P4: scan (block-local cellOff + blockSum)
    for (int task = blockIdx.x; task < 64; task += nb)
        dev_scan_task(blockHist, cellOff, blockSum, sscan, task, t);
    if (blockIdx.x == 0 && t == 0) cellOff[NC] = 0u;   // pre[64] supplies total
    gsync(bcnt, bgen, nb);
    // build 64-entry prefix once per block (persists in LDS for P5-P7)
    if (t == 0) {
        uint32_t run = 0;
        for (int i = 0; i < 64; i++) { pre[i] = run; run += blockSum[i]; }
        pre[64] = run;
    }
    __syncthreads();
    // P5: place
    for (int task = blockIdx.x; task < NB * NS; task += nb)
        dev_place_task(tbox, blockHist, cellOff, pre, pairs, F, hist, task, t);
    gsync(bcnt, bgen, nb);
    // P6: cellsort (grid-stride interleave balances the active band)
    for (int cell = blockIdx.x; cell < NC; cell += nb)
        dev_cellsort_cell(cellOff, pre, tz, pairs, F, lkeys, cell, t);
    gsync(bcnt, bgen, nb);
    // P7: raster
    int PB = (RESN * RESN) >> 8;
    for (int task = blockIdx.x; task < PB; task += nb) {
        int p = task * 256 + t;
        dev_raster_pixel(tcs, tz, cellOff, pre, pairs, basec, bg, out, F, p);
    }
}

// ================= fallback multi-kernel path (r4-proven, ~156us) ===============
__global__ __launch_bounds__(256) void k_reduce1(const bfraw* __restrict__ u, int nrows,
                                                 double* __restrict__ psum,
                                                 float* __restrict__ pmin,
                                                 float* __restrict__ pmax) {
    __shared__ double ssum[768];
    __shared__ float smin[768];
    __shared__ float smax[768];
    dev_reduce_partial(u, nrows, blockIdx.x, threadIdx.x, ssum, smin, smax,
                       psum, pmin, pmax);
}

__global__ __launch_bounds__(256) void k_reduce2(const double* __restrict__ psum,
                                                 const float* __restrict__ pmin,
                                                 const float* __restrict__ pmax,
                                                 int nrows, float* __restrict__ cst) {
    __shared__ double ssum[768];
    __shared__ float smin[768];
    __shared__ float smax[768];
    dev_reduce_final(psum, pmin, pmax, nrows, threadIdx.x, ssum, smin, smax, cst);
}

__global__ __launch_bounds__(256) void k_setup(const bfraw* __restrict__ u,
                                               const int* __restrict__ faces,
                                               const bfraw* __restrict__ mvp,
                                               const bfraw* __restrict__ light,
                                               const float* __restrict__ cst, int F,
                                               float* __restrict__ tcs,
                                               uint32_t* __restrict__ tz,
                                               uint32_t* __restrict__ tbox) {
    int f = blockIdx.x * 256 + threadIdx.x;
    if (f < F) dev_setup_one(u, faces, mvp, light, cst, f, tcs, tz, tbox);
}

__global__ __launch_bounds__(256) void k_count(const uint32_t* __restrict__ tbox,
                                               int F, u16* __restrict__ blockHist) {
    __shared__ uint32_t hist[SBINS];
    dev_count_task(tbox, F, blockHist, hist, blockIdx.x, threadIdx.x);
}

__global__ __launch_bounds__(256) void k_scanA(u16* __restrict__ blockHist,
                                               uint32_t* __restrict__ cellOff,
                                               uint32_t* __restrict__ blockSum) {
    __shared__ uint32_t sscan[256];
    dev_scan_task(blockHist, cellOff, blockSum, sscan, blockIdx.x, threadIdx.x);
}

__global__ __launch_bounds__(1024) void k_scanB(uint32_t* __restrict__ cellOff,
                                                const uint32_t* __restrict__ blockSum) {
    __shared__ uint32_t pre[65];
    int B = blockIdx.x, t = threadIdx.x;
    if (t == 0) {
        uint32_t run = 0;
        for (int i = 0; i < 64; i++) { pre[i] = run; run += blockSum[i]; }
        pre[64] = run;
    }
    __syncthreads();
    cellOff[B * 1024 + t] += pre[B];
    if (B == 63 && t == 1023) cellOff[NC] = pre[64];
}

__global__ __launch_bounds__(256) void k_place(const uint32_t* __restrict__ tbox,
                                               const u16* __restrict__ blockHist,
                                               const uint32_t* __restrict__ cellOff,
                                               uint32_t* __restrict__ pairs, int F) {
    __shared__ uint32_t hist[SBINS];
    dev_place_task(tbox, blockHist, cellOff, (const uint32_t*)nullptr, pairs, F,
                   hist, blockIdx.x, threadIdx.x);
}

__global__ __launch_bounds__(256) void k_cellsort(const uint32_t* __restrict__ cellOff,
                                                  const uint32_t* __restrict__ tz,
                                                  uint32_t* __restrict__ pairs, int F) {
    __shared__ uint64_t lkeys[CAP];
    for (int ci = 0; ci < CPB; ci++) {
        int cell = blockIdx.x + ci * (NC / CPB);   // interleaved for load balance
        dev_cellsort_cell(cellOff, (const uint32_t*)nullptr, tz, pairs, F, lkeys,
                          cell, threadIdx.x);
    }
}

__global__ __launch_bounds__(256) void k_raster(const float* __restrict__ tcs,
                                                const uint32_t* __restrict__ tz,
                                                const uint32_t* __restrict__ cellOff,
                                                const uint32_t* __restrict__ pairs,
                                                const bfraw* __restrict__ basec,
                                                const bfraw* __restrict__ bg,
                                                bfraw* __restrict__ out, int F) {
    int p = blockIdx.x * 256 + threadIdx.x;
    dev_raster_pixel(tcs, tz, cellOff, (const uint32_t*)nullptr, pairs, basec, bg,
                     out, F, p);
}

// ---------------- diagnostic: ws too small -> encode ws MB into the image -------
__global__ __launch_bounds__(256) void k_diag(bfraw* __restrict__ out, float code) {
    out[blockIdx.x * 256 + threadIdx.x] = f2bf(code);
}

extern "C" void kernel_launch(void* const* d_in, const int* in_sizes, int n_in,
                              void* d_out, int out_size, void* d_ws, size_t ws_size,
                              hipStream_t stream) {
    const bfraw* u = (const bfraw*)d_in[0];
    const bfraw* mvps = (const bfraw*)d_in[1];
    const bfraw* light = (const bfraw*)d_in[2];
    const bfraw* bg = (const bfraw*)d_in[3];
    const bfraw* basec = (const bfraw*)d_in[4];
    const int* faces = (const int*)d_in[5];
    int nrows = in_sizes[0] / 3;
    int F = in_sizes[5] / 3;
    bfraw* out = (bfraw*)d_out;

    char* w = (char*)d_ws;
    size_t off = 0;
    auto alloc = [&](size_t bytes) -> void* {
        off = (off + 255) & ~(size_t)255;
        void* p = w + off;
        off += bytes;
        return p;
    };

    float* cst = (float*)alloc(4 * sizeof(float));
    double* psum = (double*)alloc((size_t)RBLOCKS * 3 * sizeof(double));
    float* pmin = (float*)alloc((size_t)RBLOCKS * 3 * sizeof(float));
    float* pmax = (float*)alloc((size_t)RBLOCKS * 3 * sizeof(float));
    float* tcs = (float*)alloc((size_t)F * 8 * sizeof(float));
    uint32_t* tz = (uint32_t*)alloc((size_t)F * sizeof(uint32_t));
    uint32_t* tbox = (uint32_t*)alloc((size_t)F * sizeof(uint32_t));
    u16* blockHist = (u16*)alloc((size_t)NB * NC * sizeof(u16));       // 4 MB
    uint32_t* cellOff = (uint32_t*)alloc(((size_t)NC + 1) * sizeof(uint32_t));
    uint32_t* blockSum = (uint32_t*)alloc(64 * sizeof(uint32_t));
    uint32_t* pairs = (uint32_t*)alloc((size_t)F * 16 * sizeof(uint32_t));
    uint32_t* bar = (uint32_t*)alloc(2 * sizeof(uint32_t));
    size_t needed = off;  // ~15 MB for F=100k

    if (ws_size < needed) {
        // sentinel: encodes ws_size in MB (bf16-representable integers)
        float code = 20000.0f + (float)(ws_size >> 20);
        k_diag<<<(RESN * RESN * 3) / 256, 256, 0, stream>>>(out, code);
        return;
    }

    // size the persistent grid from a runtime occupancy query: guarantees all
    // blocks co-resident (manual grid barrier requirement)
    int occ = 0;
    hipError_t oe = hipOccupancyMaxActiveBlocksPerMultiprocessor(
        &occ, reinterpret_cast<const void*>(k_mega), 256, 0);
    int grid = (oe == hipSuccess && occ > 0) ? occ * 256 : 0;
    if (grid > MAXGRID) grid = MAXGRID;

    if (grid >= 256) {
        hipMemsetAsync(bar, 0, 2 * sizeof(uint32_t), stream);  // re-poison-safe
        k_mega<<<grid, 256, 0, stream>>>(u, faces, mvps, light, bg, basec,
                                         nrows, F, psum, pmin, pmax, cst, tcs,
                                         tz, tbox, blockHist, cellOff, blockSum,
                                         pairs, out, bar, bar + 1);
    } else {
        k_reduce1<<<RBLOCKS, 256, 0, stream>>>(u, nrows, psum, pmin, pmax);
        k_reduce2<<<1, 256, 0, stream>>>(psum, pmin, pmax, nrows, cst);
        k_setup<<<(F + 255) / 256, 256, 0, stream>>>(u, faces, mvps, light, cst, F,
                                                     tcs, tz, tbox);
        k_count<<<NB * NS, 256, 0, stream>>>(tbox, F, blockHist);
        k_scanA<<<64, 256, 0, stream>>>(blockHist, cellOff, blockSum);
        k_scanB<<<64, 1024, 0, stream>>>(cellOff, blockSum);
        k_place<<<NB * NS, 256, 0, stream>>>(tbox, blockHist, cellOff, pairs, F);
        k_cellsort<<<NC / CPB, 256, 0, stream>>>(cellOff, tz, pairs, F);
        k_raster<<<(RESN * RESN) / 256, 256, 0, stream>>>(tcs, tz, cellOff, pairs,
                                                          basec, bg, out, F);
    }
}

// Round 8
// 160.386 us; speedup vs baseline: 3.0913x; 3.0913x over previous
//
#include <hip/hip_runtime.h>
#include <stdint.h>

// Match numpy f32 elementwise semantics: no implicit FMA contraction.
#pragma clang fp contract(off)

#define GRIDN 256
#define NC (GRIDN * GRIDN)
#define RESN 512
#define RBLOCKS 256
#define CAP 1024      // per-cell sort capacity
#define CPB 16        // cells per cellsort block
#define NB 32         // tri chunks (chunk=3125 << u16 range)
#define NS 16         // cell-space slices (4096 cells = 16 grid rows = 8KB LDS)
#define SBINS 2048    // packed u32 bins per slice

// NOTE (r1): GLOBAL per-cell RETURNING atomics: 154->2403us. Do not retry.
// NOTE (r3): row-parallel full-tbox re-stream per grid row: 158->368us. Do not retry.
// NOTE (r5): tile-fused bin (full tbox stream per active tile): 346us. Do not retry.
// NOTE (r6): persistent kernel + RMW-spin grid barrier: 495us (spin RMWs serialize).
//   Phase math + pre[]-in-LDS indexing verified correct (absmax 0.0).
// NOTE (r7): persistent kernel w/ load-spin barrier -> container failed twice
//   (infra vs kernel unattributable). Persistent-kernel line ABANDONED.
// NOTE (r8 = this round): launch fusion without device sync: reduce2 folded into
//   setup prologue (every block redundantly finalizes cst — deterministic);
//   scanB deleted (consumers rebuild the 64-entry chunk prefix pre[] from
//   blockSum in LDS, the r6-verified mechanism). 9 -> 7 launches.

typedef unsigned short bfraw;
typedef unsigned short u16;

__device__ __forceinline__ float bf2f(bfraw h) {
    return __uint_as_float(((uint32_t)h) << 16);   // bf16 upcast is exact
}
__device__ __forceinline__ bfraw f2bf(float f) {
    uint32_t b = __float_as_uint(f);               // RNE f32 -> bf16
    return (bfraw)((b + 0x7FFFu + ((b >> 16) & 1u)) >> 16);
}
__device__ __forceinline__ uint32_t fkey(float f) {
    uint32_t b = __float_as_uint(f);
    return (b & 0x80000000u) ? ~b : (b | 0x80000000u);
}

// build the 64-chunk prefix from blockSum into LDS (r6-verified mechanism)
__device__ __forceinline__ void build_pre(const uint32_t* __restrict__ blockSum,
                                          uint32_t* pre) {
    if (threadIdx.x == 0) {
        uint32_t run = 0;
        for (int i = 0; i < 64; i++) { pre[i] = run; run += blockSum[i]; }
        pre[64] = run;   // grand total
    }
    __syncthreads();
}

// ================= shared phase bodies (all r4/r6-verified) =====================

__device__ void dev_reduce_partial(const bfraw* __restrict__ u, int nrows, int task,
                                   int t, double* ssum, float* smin, float* smax,
                                   double* __restrict__ psum,
                                   float* __restrict__ pmin,
                                   float* __restrict__ pmax) {
    double s0 = 0.0, s1 = 0.0, s2 = 0.0;
    float mn0 = INFINITY, mn1 = INFINITY, mn2 = INFINITY;
    float mx0 = -INFINITY, mx1 = -INFINITY, mx2 = -INFINITY;
    for (int r = task * 256 + t; r < nrows; r += 256 * RBLOCKS) {
        float a = bf2f(u[3 * r + 0]);
        float b = bf2f(u[3 * r + 1]);
        float c = bf2f(u[3 * r + 2]);
        s0 += (double)a; s1 += (double)b; s2 += (double)c;
        mn0 = fminf(mn0, a); mx0 = fmaxf(mx0, a);
        mn1 = fminf(mn1, b); mx1 = fmaxf(mx1, b);
        mn2 = fminf(mn2, c); mx2 = fmaxf(mx2, c);
    }
    ssum[t * 3 + 0] = s0; ssum[t * 3 + 1] = s1; ssum[t * 3 + 2] = s2;
    smin[t * 3 + 0] = mn0; smin[t * 3 + 1] = mn1; smin[t * 3 + 2] = mn2;
    smax[t * 3 + 0] = mx0; smax[t * 3 + 1] = mx1; smax[t * 3 + 2] = mx2;
    __syncthreads();
    for (int st = 128; st > 0; st >>= 1) {
        if (t < st) {
            for (int c = 0; c < 3; c++) {
                ssum[t * 3 + c] += ssum[(t + st) * 3 + c];
                smin[t * 3 + c] = fminf(smin[t * 3 + c], smin[(t + st) * 3 + c]);
                smax[t * 3 + c] = fmaxf(smax[t * 3 + c], smax[(t + st) * 3 + c]);
            }
        }
        __syncthreads();
    }
    if (t == 0) {
        for (int c = 0; c < 3; c++) {
            psum[task * 3 + c] = ssum[c];
            pmin[task * 3 + c] = smin[c];
            pmax[task * 3 + c] = smax[c];
        }
    }
    __syncthreads();
}

// deterministic: every block computes bit-identical cst from the same partials
__device__ void dev_reduce_final(const double* __restrict__ psum,
                                 const float* __restrict__ pmin,
                                 const float* __restrict__ pmax,
                                 int nrows, int t,
                                 double* ssum, float* smin, float* smax,
                                 float* __restrict__ cst) {
    for (int c = 0; c < 3; c++) {
        ssum[t * 3 + c] = psum[t * 3 + c];
        smin[t * 3 + c] = pmin[t * 3 + c];
        smax[t * 3 + c] = pmax[t * 3 + c];
    }
    __syncthreads();
    for (int st = 128; st > 0; st >>= 1) {
        if (t < st) {
            for (int c = 0; c < 3; c++) {
                ssum[t * 3 + c] += ssum[(t + st) * 3 + c];
                smin[t * 3 + c] = fminf(smin[t * 3 + c], smin[(t + st) * 3 + c]);
                smax[t * 3 + c] = fmaxf(smax[t * 3 + c], smax[(t + st) * 3 + c]);
            }
        }
        __syncthreads();
    }
    if (t == 0) {
        float fn = (float)nrows;
        float m0 = (float)ssum[0] / fn;
        float m1 = (float)ssum[1] / fn;
        float m2 = (float)ssum[2] / fn;
        // fp32 rounding is monotone: max_r(u - mean) == colmax - mean exactly.
        float vmax = fmaxf(fmaxf(smax[0] - m0, smax[1] - m1), smax[2] - m2);
        float vmin = fminf(fminf(smin[0] - m0, smin[1] - m1), smin[2] - m2);
        float span = fmaxf(vmax - vmin, 1e-06f);
        float s = 0.5f / span;   // SCALE / span
        cst[0] = m0; cst[1] = m1; cst[2] = m2; cst[3] = s;
    }
    __syncthreads();
}

// tcs layout per tri (8 floats): cpx0,cpy0,cpx1,cpy1,cpx2,cpy2,shade,0
// tbox: lox | loy<<8 | hx<<16 | hy<<24  with hx=min(hix,lox+3), hy=min(hiy,loy+3)
__device__ void dev_setup_one(const bfraw* __restrict__ u,
                              const int* __restrict__ faces,
                              const bfraw* __restrict__ mvp,
                              const bfraw* __restrict__ light,
                              const float* __restrict__ cst, int f,
                              float* __restrict__ tcs,
                              uint32_t* __restrict__ tz,
                              uint32_t* __restrict__ tbox) {
    float m0 = cst[0], m1 = cst[1], m2 = cst[2], s = cst[3];
    float M[12];
    for (int i = 0; i < 12; i++) M[i] = bf2f(mvp[i]);

    float vx[3], vy[3], vz[3], cpx[3], cpy[3], zc[3];
    for (int j = 0; j < 3; j++) {
        int idx = faces[3 * f + j];
        float a = bf2f(u[3 * idx + 0]);
        float b = bf2f(u[3 * idx + 1]);
        float c = bf2f(u[3 * idx + 2]);
        float x = (a - m0) * s;
        float y = (b - m1) * s;
        float z = (c - m2) * s;
        vx[j] = x; vy[j] = y; vz[j] = z;
        // BLAS-style ascending-k fma chain; w=1 -> plain add of M[row][3]
        float cx = fmaf(x, M[0], 0.0f);
        cx = fmaf(y, M[1], cx); cx = fmaf(z, M[2], cx); cx = cx + M[3];
        float cy = fmaf(x, M[4], 0.0f);
        cy = fmaf(y, M[5], cy); cy = fmaf(z, M[6], cy); cy = cy + M[7];
        float cz = fmaf(x, M[8], 0.0f);
        cz = fmaf(y, M[9], cz); cz = fmaf(z, M[10], cz); cz = cz + M[11];
        cpx[j] = (cx + 1.0f) * 0.5f;
        cpy[j] = (cy + 1.0f) * 0.5f;
        zc[j] = cz;
    }
    float zmean = ((zc[0] + zc[1]) + zc[2]) / 3.0f;

    float e1x = vx[0] - vx[1], e1y = vy[0] - vy[1], e1z = vz[0] - vz[1];
    float e2x = vx[2] - vx[1], e2y = vy[2] - vy[1], e2z = vz[2] - vz[1];
    float nx = e1y * e2z - e1z * e2y;
    float ny = e1z * e2x - e1x * e2z;
    float nz = e1x * e2y - e1y * e2x;
    float nn = nx * nx;
    nn = nn + ny * ny;
    nn = nn + nz * nz;
    float d = sqrtf(nn) + 1e-10f;
    float inx = nx / d, iny = ny / d, inz = nz / d;

    float l0 = bf2f(light[0]), l1 = bf2f(light[1]), l2 = bf2f(light[2]);
    float p0 = (-l0) * inx;
    float p1 = (-l1) * iny;
    float p2 = (-l2) * inz;
    float shading = fmaxf((p0 + p1) + p2, 0.0f);

    tcs[f * 8 + 0] = cpx[0]; tcs[f * 8 + 1] = cpy[0];
    tcs[f * 8 + 2] = cpx[1]; tcs[f * 8 + 3] = cpy[1];
    tcs[f * 8 + 4] = cpx[2]; tcs[f * 8 + 5] = cpy[2];
    tcs[f * 8 + 6] = shading;
    tcs[f * 8 + 7] = 0.0f;

    tz[f] = fkey(zmean);

    float mnx = fminf(fminf(cpx[0], cpx[1]), cpx[2]);
    float mny = fminf(fminf(cpy[0], cpy[1]), cpy[2]);
    float mxx = fmaxf(fmaxf(cpx[0], cpx[1]), cpx[2]);
    float mxy = fmaxf(fmaxf(cpy[0], cpy[1]), cpy[2]);
    int lox = (int)floorf(mnx * 256.0f); lox = lox < 0 ? 0 : (lox > 255 ? 255 : lox);
    int loy = (int)floorf(mny * 256.0f); loy = loy < 0 ? 0 : (loy > 255 ? 255 : loy);
    int hix = (int)floorf(mxx * 256.0f); hix = hix < 0 ? 0 : (hix > 255 ? 255 : hix);
    int hiy = (int)floorf(mxy * 256.0f); hiy = hiy < 0 ? 0 : (hiy > 255 ? 255 : hiy);
    int hx = hix < lox + 3 ? hix : lox + 3;   // SPAN=4 window
    int hy = hiy < loy + 3 ? hiy : loy + 3;
    tbox[f] = (uint32_t)lox | ((uint32_t)loy << 8) | ((uint32_t)hx << 16) | ((uint32_t)hy << 24);
}

// slice sl owns grid rows [16*sl,16*sl+16): y-loop clamped, no per-cell filter
__device__ void dev_count_task(const uint32_t* __restrict__ tbox, int F,
                               u16* __restrict__ blockHist, uint32_t* hist,
                               int task, int t) {
    int b = task >> 4;
    int sl = task & (NS - 1);
    int chunk = (F + NB - 1) / NB;
    int fs = b * chunk;
    int fe = fs + chunk < F ? fs + chunk : F;
    int y0 = sl * 16, y1 = y0 + 15;
    for (int i = t; i < SBINS; i += 256) hist[i] = 0u;
    __syncthreads();
    for (int f = fs + t; f < fe; f += 256) {
        uint32_t bx = tbox[f];
        int lox = bx & 255, loy = (bx >> 8) & 255;
        int hx = (bx >> 16) & 255, hy = bx >> 24;
        int ys = loy > y0 ? loy : y0;
        int ye = hy < y1 ? hy : y1;
        for (int yy = ys; yy <= ye; yy++) {
            for (int xx = lox; xx <= hx; xx++) {
                uint32_t c = (uint32_t)(yy * GRIDN + xx) & 4095u;
                atomicAdd(&hist[c >> 1], 1u << (16u * (c & 1u)));
            }
        }
    }
    __syncthreads();
    uint32_t* dst = (uint32_t*)(blockHist + (size_t)b * NC) + sl * SBINS;
    for (int i = t; i < SBINS; i += 256) dst[i] = hist[i];
    __syncthreads();
}

// scan task B: cells [B*1024, B*1024+1024), 4 cells/thread; writes block-LOCAL
// exclusive cellOff + blockSum[B]; blockHist entries become per-(chunk,cell) base
__device__ void dev_scan_task(u16* __restrict__ blockHist,
                              uint32_t* __restrict__ cellOff,
                              uint32_t* __restrict__ blockSum,
                              uint32_t* sscan, int task, int t) {
    int c0 = task * 1024 + t * 4;
    uint32_t tot[4];
    uint32_t tsum = 0;
    for (int k = 0; k < 4; k++) {
        uint32_t tt = 0;
        for (int b = 0; b < NB; b++) {
            size_t o = (size_t)b * NC + (c0 + k);
            uint32_t v = blockHist[o];
            blockHist[o] = (u16)tt;
            tt += v;
        }
        tot[k] = tt;
        tsum += tt;
    }
    sscan[t] = tsum;
    __syncthreads();
    for (int st = 1; st < 256; st <<= 1) {
        uint32_t a = 0;
        if (t >= st) a = sscan[t - st];
        __syncthreads();
        if (t >= st) sscan[t] += a;
        __syncthreads();
    }
    uint32_t run = sscan[t] - tsum;   // exclusive
    for (int k = 0; k < 4; k++) {
        cellOff[c0 + k] = run;
        run += tot[k];
    }
    if (t == 255) blockSum[task] = sscan[255];
    __syncthreads();
}

__device__ void dev_place_task(const uint32_t* __restrict__ tbox,
                               const u16* __restrict__ blockHist,
                               const uint32_t* __restrict__ cellOff,
                               const uint32_t* pre,
                               uint32_t* __restrict__ pairs, int F,
                               uint32_t* hist, int task, int t) {
    int b = task >> 4;
    int sl = task & (NS - 1);
    int chunk = (F + NB - 1) / NB;
    int fs = b * chunk;
    int fe = fs + chunk < F ? fs + chunk : F;
    int y0 = sl * 16, y1 = y0 + 15;
    uint32_t pcap = (uint32_t)F * 16u;
    for (int i = t; i < SBINS; i += 256) hist[i] = 0u;
    __syncthreads();
    for (int f = fs + t; f < fe; f += 256) {
        uint32_t bx = tbox[f];
        int lox = bx & 255, loy = (bx >> 8) & 255;
        int hx = (bx >> 16) & 255, hy = bx >> 24;
        int ys = loy > y0 ? loy : y0;
        int ye = hy < y1 ? hy : y1;
        for (int yy = ys; yy <= ye; yy++) {
            for (int xx = lox; xx <= hx; xx++) {
                uint32_t cell = (uint32_t)(yy * GRIDN + xx);
                uint32_t c = cell & 4095u;
                uint32_t sh = 16u * (c & 1u);
                uint32_t old = atomicAdd(&hist[c >> 1], 1u << sh);
                uint32_t r = (old >> sh) & 0xFFFFu;
                uint32_t base = cellOff[cell] + pre[cell >> 10];
                uint32_t pos = base + (uint32_t)blockHist[(size_t)b * NC + cell] + r;
                if (pos < pcap) pairs[pos] = (uint32_t)f;   // defensive vs poisoned replay
            }
        }
    }
    __syncthreads();
}

// top-64 selection for cells with n>64 ONLY; rank-write leaves survivors SORTED
__device__ void dev_cellsort_cell(const uint32_t* __restrict__ cellOff,
                                  const uint32_t* pre,
                                  const uint32_t* __restrict__ tz,
                                  uint32_t* __restrict__ pairs, int F,
                                  uint64_t* lkeys, int cell, int t) {
    uint32_t pcap = (uint32_t)F * 16u;
    uint32_t off = cellOff[cell] + pre[cell >> 10];
    uint32_t end = cellOff[cell + 1] + pre[(cell + 1) >> 10];
    if (off > pcap || end > pcap || end < off) return;   // defensive (uniform)
    uint32_t n = end - off;
    if (n <= 64u) return;             // no truncation -> no sort needed
    uint32_t m = n > CAP ? CAP : n;
    for (uint32_t i = t; i < m; i += 256) {
        uint32_t id = pairs[off + i];
        if (id >= (uint32_t)F) id = 0;   // defensive
        lkeys[i] = ((uint64_t)tz[id] << 32) | id;
    }
    __syncthreads();
    uint64_t k0 = ~0ull, k1 = ~0ull, k2 = ~0ull, k3 = ~0ull;
    uint32_t i0 = t, i1 = t + 256, i2 = t + 512, i3 = t + 768;
    if (i0 < m) k0 = lkeys[i0];
    if (i1 < m) k1 = lkeys[i1];
    if (i2 < m) k2 = lkeys[i2];
    if (i3 < m) k3 = lkeys[i3];
    uint32_t r0 = 0, r1 = 0, r2 = 0, r3 = 0;
    for (uint32_t j = 0; j < m; j++) {
        uint64_t kj = lkeys[j];   // broadcast: conflict-free
        r0 += (kj < k0) ? 1u : 0u;
        r1 += (kj < k1) ? 1u : 0u;
        r2 += (kj < k2) ? 1u : 0u;
        r3 += (kj < k3) ? 1u : 0u;
    }
    if (i0 < m && r0 < 64u) pairs[off + r0] = (uint32_t)(k0 & 0xFFFFFFFFu);
    if (i1 < m && r1 < 64u) pairs[off + r1] = (uint32_t)(k1 & 0xFFFFFFFFu);
    if (i2 < m && r2 < 64u) pairs[off + r2] = (uint32_t)(k2 & 0xFFFFFFFFu);
    if (i3 < m && r3 < 64u) pairs[off + r3] = (uint32_t)(k3 & 0xFFFFFFFFu);
    __syncthreads();   // protect lkeys before next cell's staging (uniform)
}

// raster: first-hit (sorted, n>64) / argmin (unsorted, n<=64) — r3 invariant
__device__ void dev_raster_pixel(const float* __restrict__ tcs,
                                 const uint32_t* __restrict__ tz,
                                 const uint32_t* __restrict__ cellOff,
                                 const uint32_t* pre,
                                 const uint32_t* __restrict__ pairs,
                                 const bfraw* __restrict__ basec,
                                 const bfraw* __restrict__ bg,
                                 bfraw* __restrict__ out, int F, int p) {
    int col = p & (RESN - 1);
    int row = p >> 9;
    float px = ((float)col + 0.5f) / 512.0f;
    float py = ((float)row + 0.5f) / 512.0f;
    int cell = (row >> 1) * GRIDN + (col >> 1);
    uint32_t pcap = (uint32_t)F * 16u;
    uint32_t off = cellOff[cell] + pre[cell >> 10];
    uint32_t end = cellOff[cell + 1] + pre[(cell + 1) >> 10];
    uint32_t n = 0;
    if (off <= pcap && end <= pcap && end >= off) n = end - off;
    uint32_t m = n > 64u ? 64u : n;
    bool srt = n > 64u;
    uint64_t best = ~0ull;
    uint32_t bestId = 0u;
    float bestSh = 0.0f;
    bool found = false;
    for (uint32_t k = 0; k < m; k++) {
        uint32_t id = pairs[off + k];
        if (id >= (uint32_t)F) continue;   // defensive
        const float4 A = *(const float4*)(tcs + (size_t)id * 8);
        const float4 B = *(const float4*)(tcs + (size_t)id * 8 + 4);
        float ax = A.x, ay = A.y, bx = A.z, by = A.w, cx = B.x, cy = B.y;
        float e0 = (bx - ax) * (py - ay) - (by - ay) * (px - ax);
        float e1 = (cx - bx) * (py - by) - (cy - by) * (px - bx);
        float e2 = (ax - cx) * (py - cy) - (ay - cy) * (px - cx);
        bool inside = (e0 >= 0.0f && e1 >= 0.0f && e2 >= 0.0f) ||
                      (e0 <= 0.0f && e1 <= 0.0f && e2 <= 0.0f);
        if (inside) {
            if (srt) { bestId = id; bestSh = B.z; found = true; break; }
            uint64_t key = ((uint64_t)tz[id] << 32) | id;
            if (key < best) { best = key; bestId = id; bestSh = B.z; found = true; }
        }
    }
    float r, g, b;
    if (found) {
        r = bf2f(basec[3 * bestId + 0]) * bestSh;
        g = bf2f(basec[3 * bestId + 1]) * bestSh;
        b = bf2f(basec[3 * bestId + 2]) * bestSh;
    } else {
        r = bf2f(bg[0]); g = bf2f(bg[1]); b = bf2f(bg[2]);
    }
    int o = p * 3;
    out[o + 0] = f2bf(r);
    out[o + 1] = f2bf(g);
    out[o + 2] = f2bf(b);
}

// ================= 7-launch pipeline ===========================================

__global__ __launch_bounds__(256) void k_reduce1(const bfraw* __restrict__ u, int nrows,
                                                 double* __restrict__ psum,
                                                 float* __restrict__ pmin,
                                                 float* __restrict__ pmax) {
    __shared__ double ssum[768];
    __shared__ float smin[768];
    __shared__ float smax[768];
    dev_reduce_partial(u, nrows, blockIdx.x, threadIdx.x, ssum, smin, smax,
                       psum, pmin, pmax);
}

// setup with fused cst-finalize: every block redundantly reduces the 256
// partials (deterministic, bit-identical) — removes the 1-block k_reduce2 launch
__global__ __launch_bounds__(256) void k_setup(const bfraw* __restrict__ u,
                                               const int* __restrict__ faces,
                                               const bfraw* __restrict__ mvp,
                                               const bfraw* __restrict__ light,
                                               const double* __restrict__ psum,
                                               const float* __restrict__ pmin,
                                               const float* __restrict__ pmax,
                                               int nrows, int F,
                                               float* __restrict__ tcs,
                                               uint32_t* __restrict__ tz,
                                               uint32_t* __restrict__ tbox) {
    __shared__ double ssum[768];
    __shared__ float smin[768];
    __shared__ float smax[768];
    __shared__ float lcst[4];
    dev_reduce_final(psum, pmin, pmax, nrows, threadIdx.x, ssum, smin, smax, lcst);
    int f = blockIdx.x * 256 + threadIdx.x;
    if (f < F) dev_setup_one(u, faces, mvp, light, lcst, f, tcs, tz, tbox);
}

__global__ __launch_bounds__(256) void k_count(const uint32_t* __restrict__ tbox,
                                               int F, u16* __restrict__ blockHist) {
    __shared__ uint32_t hist[SBINS];
    dev_count_task(tbox, F, blockHist, hist, blockIdx.x, threadIdx.x);
}

// scan: block-local cellOff + blockSum; consumers add pre[] themselves.
// Block 63 also zeroes cellOff[NC] (end sentinel: end = 0 + pre[64] = total).
__global__ __launch_bounds__(256) void k_scanA(u16* __restrict__ blockHist,
                                               uint32_t* __restrict__ cellOff,
                                               uint32_t* __restrict__ blockSum) {
    __shared__ uint32_t sscan[256];
    dev_scan_task(blockHist, cellOff, blockSum, sscan, blockIdx.x, threadIdx.x);
    if (blockIdx.x == 63 && threadIdx.x == 255) cellOff[NC] = 0u;
}

__global__ __launch_bounds__(256) void k_place(const uint32_t* __restrict__ tbox,
                                               const u16* __restrict__ blockHist,
                                               const uint32_t* __restrict__ cellOff,
                                               const uint32_t* __restrict__ blockSum,
                                               uint32_t* __restrict__ pairs, int F) {
    __shared__ uint32_t hist[SBINS];
    __shared__ uint32_t pre[65];
    build_pre(blockSum, pre);
    dev_place_task(tbox, blockHist, cellOff, pre, pairs, F, hist,
                   blockIdx.x, threadIdx.x);
}

__global__ __launch_bounds__(256) void k_cellsort(const uint32_t* __restrict__ cellOff,
                                                  const uint32_t* __restrict__ blockSum,
                                                  const uint32_t* __restrict__ tz,
                                                  uint32_t* __restrict__ pairs, int F) {
    __shared__ uint64_t lkeys[CAP];
    __shared__ uint32_t pre[65];
    build_pre(blockSum, pre);
    for (int ci = 0; ci < CPB; ci++) {
        int cell = blockIdx.x + ci * (NC / CPB);   // interleaved for load balance
        dev_cellsort_cell(cellOff, pre, tz, pairs, F, lkeys, cell, threadIdx.x);
    }
}

__global__ __launch_bounds__(256) void k_raster(const float* __restrict__ tcs,
                                                const uint32_t* __restrict__ tz,
                                                const uint32_t* __restrict__ cellOff,
                                                const uint32_t* __restrict__ blockSum,
                                                const uint32_t* __restrict__ pairs,
                                                const bfraw* __restrict__ basec,
                                                const bfraw* __restrict__ bg,
                                                bfraw* __restrict__ out, int F) {
    __shared__ uint32_t pre[65];
    build_pre(blockSum, pre);
    int p = blockIdx.x * 256 + threadIdx.x;
    dev_raster_pixel(tcs, tz, cellOff, pre, pairs, basec, bg, out, F, p);
}

// ---------------- diagnostic: ws too small -> encode ws MB into the image -------
__global__ __launch_bounds__(256) void k_diag(bfraw* __restrict__ out, float code) {
    out[blockIdx.x * 256 + threadIdx.x] = f2bf(code);
}

extern "C" void kernel_launch(void* const* d_in, const int* in_sizes, int n_in,
                              void* d_out, int out_size, void* d_ws, size_t ws_size,
                              hipStream_t stream) {
    const bfraw* u = (const bfraw*)d_in[0];
    const bfraw* mvps = (const bfraw*)d_in[1];
    const bfraw* light = (const bfraw*)d_in[2];
    const bfraw* bg = (const bfraw*)d_in[3];
    const bfraw* basec = (const bfraw*)d_in[4];
    const int* faces = (const int*)d_in[5];
    int nrows = in_sizes[0] / 3;
    int F = in_sizes[5] / 3;
    bfraw* out = (bfraw*)d_out;

    char* w = (char*)d_ws;
    size_t off = 0;
    auto alloc = [&](size_t bytes) -> void* {
        off = (off + 255) & ~(size_t)255;
        void* p = w + off;
        off += bytes;
        return p;
    };

    double* psum = (double*)alloc((size_t)RBLOCKS * 3 * sizeof(double));
    float* pmin = (float*)alloc((size_t)RBLOCKS * 3 * sizeof(float));
    float* pmax = (float*)alloc((size_t)RBLOCKS * 3 * sizeof(float));
    float* tcs = (float*)alloc((size_t)F * 8 * sizeof(float));
    uint32_t* tz = (uint32_t*)alloc((size_t)F * sizeof(uint32_t));
    uint32_t* tbox = (uint32_t*)alloc((size_t)F * sizeof(uint32_t));
    u16* blockHist = (u16*)alloc((size_t)NB * NC * sizeof(u16));       // 4 MB
    uint32_t* cellOff = (uint32_t*)alloc(((size_t)NC + 1) * sizeof(uint32_t));
    uint32_t* blockSum = (uint32_t*)alloc(64 * sizeof(uint32_t));
    uint32_t* pairs = (uint32_t*)alloc((size_t)F * 16 * sizeof(uint32_t));
    size_t needed = off;  // ~15 MB for F=100k

    if (ws_size < needed) {
        // sentinel: encodes ws_size in MB (bf16-representable integers)
        float code = 20000.0f + (float)(ws_size >> 20);
        k_diag<<<(RESN * RESN * 3) / 256, 256, 0, stream>>>(out, code);
        return;
    }

    k_reduce1<<<RBLOCKS, 256, 0, stream>>>(u, nrows, psum, pmin, pmax);
    k_setup<<<(F + 255) / 256, 256, 0, stream>>>(u, faces, mvps, light,
                                                 psum, pmin, pmax, nrows, F,
                                                 tcs, tz, tbox);
    k_count<<<NB * NS, 256, 0, stream>>>(tbox, F, blockHist);
    k_scanA<<<64, 256, 0, stream>>>(blockHist, cellOff, blockSum);
    k_place<<<NB * NS, 256, 0, stream>>>(tbox, blockHist, cellOff, blockSum,
                                         pairs, F);
    k_cellsort<<<NC / CPB, 256, 0, stream>>>(cellOff, blockSum, tz, pairs, F);
    k_raster<<<(RESN * RESN) / 256, 256, 0, stream>>>(tcs, tz, cellOff, blockSum,
                                                      pairs, basec, bg, out, F);
}